// Round 1
// 247.148 us; speedup vs baseline: 1.0085x; 1.0085x over previous
//
#include <hip/hip_runtime.h>

// SNN membrane scan + spike + double-cumsum, two-phase fused kernel.
//
// Phase A: wave 0 of each block runs the exact sequential membrane recurrence
//          (pure loads, no global stores -> full vmcnt window for reads),
//          packing spikes as bitmasks into LDS (1 bit/timestep).
// Phase B: all 8 waves; wave w reconstructs integer carries (c1, z) for its
//          128-timestep chunk from the LDS bitmasks (exact int math), then
//          streams gz/zo stores. 8 waves/CU of fire-and-forget stores.
//
// m recurrence order and fmaf are identical to the previous kernel -> bit-exact.

#define T_LEN 1024
#define N_IN  512
#define BN    16384   // BATCH * N_IN
#define U     16      // timesteps per pipeline stage

struct Buf { float c[U]; float v[U]; };

__device__ __forceinline__ void prefetch(Buf& b, const float* __restrict__ cp,
                                         const float* __restrict__ vp, int t0) {
    const float* __restrict__ c = cp + (size_t)t0 * BN;
    const float* __restrict__ v = vp + (size_t)t0 * BN;
#pragma unroll
    for (int u = 0; u < U; ++u) {
        b.c[u] = c[(size_t)u * BN];
        b.v[u] = v[(size_t)u * BN];
    }
}

// Advance membrane 16 steps; return 16-bit spike mask (bit u = spike at t0+u).
__device__ __forceinline__ unsigned process16(const Buf& b, float beta, float& m) {
    unsigned mask = 0u;
#pragma unroll
    for (int u = 0; u < U; ++u) {
        m = fmaf(beta, m, b.c[u]);              // exact same op/order as before
        mask |= (m >= b.v[u]) ? (1u << u) : 0u; // Heaviside(m - vth)
    }
    return mask;
}

__global__ __launch_bounds__(512, 2) void snn_scan(
        const float* __restrict__ cur, const float* __restrict__ beta,
        const float* __restrict__ vini, const float* __restrict__ vth,
        float* __restrict__ gz, float* __restrict__ zo, float* __restrict__ ml)
{
    __shared__ unsigned bits[T_LEN / 32][64];   // 8 KiB: [dword][channel-lane]

    const int lane = threadIdx.x & 63;
    const int wave = threadIdx.x >> 6;          // 0..7
    const int i = blockIdx.x * 64 + lane;       // channel id (= b*N + n)

    // ---------------- Phase A: sequential membrane scan (wave 0 only) -------
    if (wave == 0) {
        const float bta = beta[i & (N_IN - 1)];
        float m = vini[i];
        const float* cp = cur + i;
        const float* vp = vth + i;

        Buf b0, b1, b2, b3;
        prefetch(b0, cp, vp, 0);
        prefetch(b1, cp, vp, U);
        prefetch(b2, cp, vp, 2 * U);
        prefetch(b3, cp, vp, 3 * U);

        for (int t0 = 0; t0 < T_LEN; t0 += 4 * U) {
            unsigned m0 = process16(b0, bta, m);
            if (t0 + 4 * U < T_LEN) prefetch(b0, cp, vp, t0 + 4 * U);
            unsigned m1 = process16(b1, bta, m);
            if (t0 + 5 * U < T_LEN) prefetch(b1, cp, vp, t0 + 5 * U);
            bits[t0 >> 5][lane] = m0 | (m1 << 16);          // t0 % 64 == 0
            unsigned m2 = process16(b2, bta, m);
            if (t0 + 6 * U < T_LEN) prefetch(b2, cp, vp, t0 + 6 * U);
            unsigned m3 = process16(b3, bta, m);
            if (t0 + 7 * U < T_LEN) prefetch(b3, cp, vp, t0 + 7 * U);
            bits[(t0 >> 5) + 1][lane] = m2 | (m3 << 16);
        }
        ml[i] = m;   // m_last (B,N)
    }
    __syncthreads();

    // ---------------- Phase B: carries + output streaming (all 8 waves) -----
    // Wave w owns timesteps [128w, 128w+128) = LDS dwords [4w, 4w+4).
    int C = 0;   // c1 carry: total spikes before this chunk
    int Z = 0;   // z  carry: z value at last timestep before this chunk
    const int d0 = wave * 4;
    for (int d = 0; d < d0; ++d) {
        unsigned u = bits[d][lane];
#pragma unroll
        for (int b = 0; b < 32; ++b) {   // exact integer replay of c1/z
            C += (u >> b) & 1u;
            Z += C;
        }
    }

    float* __restrict__ gp = gz + (size_t)(d0 * 32) * BN + i;
    float* __restrict__ zp = zo + (size_t)(d0 * 32) * BN + i;
    for (int d = 0; d < 4; ++d) {
        unsigned u = bits[d0 + d][lane];
#pragma unroll
        for (int b = 0; b < 32; ++b) {
            C += (u >> b) & 1u;
            Z += C;
            const size_t off = (size_t)(d * 32 + b) * BN;
            gp[off] = (Z == 1) ? 1.0f : 0.0f;   // Block.g forward value
            zp[off] = (float)Z;                 // exact: z < 2^24
        }
    }
}

extern "C" void kernel_launch(void* const* d_in, const int* in_sizes, int n_in,
                              void* d_out, int out_size, void* d_ws, size_t ws_size,
                              hipStream_t stream) {
    const float* cur  = (const float*)d_in[0];   // (T,B,N) fp32
    const float* beta = (const float*)d_in[1];   // (N,)
    const float* vini = (const float*)d_in[2];   // (B,N)
    const float* vth  = (const float*)d_in[3];   // (T,B,N)
    float* gz = (float*)d_out;                       // (T,B,N)
    float* zo = gz + (size_t)T_LEN * BN;             // (T,B,N)
    float* ml = zo + (size_t)T_LEN * BN;             // (B,N)
    snn_scan<<<BN / 64, 512, 0, stream>>>(cur, beta, vini, vth, gz, zo, ml);
}